// Round 1
// baseline (3005.745 us; speedup 1.0000x reference)
//
#include <hip/hip_runtime.h>

#define EC 1048576   // conformer edges
#define NN 65536     // conformer nodes
#define NT 8192      // topo nodes
#define NCONF_ 2048
#define MM 256
#define HH 128
#define FF 64
#define GG 50
#define EG 32768     // graph edges

constexpr float STEP = 10.0f / 49.0f;
constexpr float GC = -0.5f / (STEP * STEP);

// ---------------- edge geometry: ew, cosine window ----------------
__global__ __launch_bounds__(256) void edge_geom_kernel(
    const float* __restrict__ pos, const int* __restrict__ ei,
    float* __restrict__ ew, float* __restrict__ cwin)
{
    int e = blockIdx.x * 256 + threadIdx.x;
    int r = ei[e], c = ei[EC + e];
    float dx = pos[r*3+0] - pos[c*3+0];
    float dy = pos[r*3+1] - pos[c*3+1];
    float dz = pos[r*3+2] - pos[c*3+2];
    float w = sqrtf(dx*dx + dy*dy + dz*dz + 1e-12f);
    ew[e] = w;
    cwin[e] = 0.5f * (__cosf(w * (3.14159265358979323846f / 10.0f)) + 1.0f);
}

// ---------------- atom embedding broadcast ----------------
__global__ __launch_bounds__(256) void embed_kernel(
    const float* __restrict__ emb, const int* __restrict__ xtopo,
    const int* __restrict__ cnb, float* __restrict__ x)
{
    int idx = blockIdx.x * 256 + threadIdx.x;
    int n = idx >> 7, f = idx & 127;
    x[idx] = emb[xtopo[cnb[n]] * HH + f];
}

// ---------------- generic fp32 GEMM: C = A[MxK] @ B[KxN] (+bias)(+res)(relu) ----------------
// flags: 1 = relu, 2 = add residual `res` (same layout as C)
__global__ __launch_bounds__(256) void gemm_kernel(
    const float* __restrict__ A, const float* __restrict__ B,
    const float* __restrict__ bias, const float* __restrict__ res,
    float* __restrict__ C, int M, int N, int K, int flags)
{
    __shared__ float As[16][68];
    __shared__ float Bs[16][68];
    int tid = threadIdx.x;
    int m0 = blockIdx.y * 64, n0 = blockIdx.x * 64;
    int la_m = tid >> 2;            // 0..63 row within tile
    int la_k = (tid & 3) * 4;       // 0,4,8,12
    int lb_k = tid >> 4;            // 0..15
    int lb_n = (tid & 15) * 4;      // 0..60
    int tx = tid & 15, ty = tid >> 4;
    float acc[4][4] = {};
    const float* Ap = A + (size_t)(m0 + la_m) * K + la_k;
    const float* Bp = B + (size_t)lb_k * N + n0 + lb_n;
    for (int k0 = 0; k0 < K; k0 += 16) {
        float4 av = *(const float4*)(Ap + k0);
        float4 bv = *(const float4*)(Bp + (size_t)k0 * N);
        __syncthreads();
        As[la_k+0][la_m] = av.x; As[la_k+1][la_m] = av.y;
        As[la_k+2][la_m] = av.z; As[la_k+3][la_m] = av.w;
        *(float4*)&Bs[lb_k][lb_n] = bv;
        __syncthreads();
        #pragma unroll
        for (int kk = 0; kk < 16; kk++) {
            float4 a = *(const float4*)&As[kk][ty*4];
            float4 b = *(const float4*)&Bs[kk][tx*4];
            float ar[4] = {a.x, a.y, a.z, a.w};
            float br[4] = {b.x, b.y, b.z, b.w};
            #pragma unroll
            for (int i = 0; i < 4; i++)
                #pragma unroll
                for (int j = 0; j < 4; j++)
                    acc[i][j] = fmaf(ar[i], br[j], acc[i][j]);
        }
    }
    #pragma unroll
    for (int i = 0; i < 4; i++) {
        int row = m0 + ty*4 + i;
        #pragma unroll
        for (int j = 0; j < 4; j++) {
            int col = n0 + tx*4 + j;
            float v = acc[i][j];
            if (bias) v += bias[col];
            if (flags & 2) v += res[(size_t)row * N + col];
            if (flags & 1) v = fmaxf(v, 0.f);
            C[(size_t)row * N + col] = v;
        }
    }
}

// ---------------- fused edge MLP + gather*mul + scatter-add ----------------
// one wave (64 threads) per 64 edges; thread computes one edge's 64-dim filter.
__global__ __launch_bounds__(64) void edge_mlp_agg_kernel(
    const float* __restrict__ ew, const float* __restrict__ cwin,
    const int* __restrict__ ei,
    const float* __restrict__ w1, const float* __restrict__ b1,
    const float* __restrict__ w2, const float* __restrict__ b2,
    const float* __restrict__ h1, float* __restrict__ agg)
{
    __shared__ float buf[64 * 65];
    __shared__ int rs[64], cs[64];
    int lane = threadIdx.x;
    int e = blockIdx.x * 64 + lane;
    float w = ew[e], cw = cwin[e];
    rs[lane] = ei[e];
    cs[lane] = ei[EC + e];
    // t = ea @ W1 + b1   (weights are thread-uniform -> scalar loads)
    float t[64];
    #pragma unroll
    for (int j = 0; j < 64; j++) t[j] = b1[j];
    for (int g = 0; g < GG; g++) {
        float d = w - g * STEP;
        float ea = __expf(GC * d * d);
        const float* w1g = w1 + g * 64;
        #pragma unroll
        for (int j = 0; j < 64; j++) t[j] = fmaf(ea, w1g[j], t[j]);
    }
    // stage relu(t) in LDS (stride 65 -> conflict-free), then wf = t @ W2 + b2
    #pragma unroll
    for (int j = 0; j < 64; j++) buf[lane * 65 + j] = fmaxf(t[j], 0.f);
    __syncthreads();
    float wf[64];
    #pragma unroll
    for (int j = 0; j < 64; j++) wf[j] = b2[j];
    for (int i = 0; i < 64; i++) {
        float ti = buf[lane * 65 + i];
        const float* w2i = w2 + i * 64;
        #pragma unroll
        for (int j = 0; j < 64; j++) wf[j] = fmaf(ti, w2i[j], wf[j]);
    }
    __syncthreads();
    #pragma unroll
    for (int j = 0; j < 64; j++) buf[lane * 65 + j] = wf[j] * cw;
    __syncthreads();
    // cooperative phase: per edge, coalesced h1-row load, coalesced atomic add
    for (int e2 = 0; e2 < 64; e2++) {
        int r2 = rs[e2], c2 = cs[e2];
        float v = h1[(size_t)r2 * 64 + lane] * buf[e2 * 65 + lane];
        atomicAdd(&agg[(size_t)c2 * 64 + lane], v);
    }
}

// ---------------- segment_max via order-preserving uint encoding ----------------
__global__ __launch_bounds__(256) void encode_max_kernel(
    const float* __restrict__ x, const int* __restrict__ cnb,
    unsigned int* __restrict__ enc)
{
    int idx = blockIdx.x * 256 + threadIdx.x;
    int n = idx >> 7, f = idx & 127;
    unsigned int b = __float_as_uint(x[idx]);
    unsigned int e = (b & 0x80000000u) ? ~b : (b | 0x80000000u);
    atomicMax(&enc[cnb[n] * HH + f], e);
}

__global__ __launch_bounds__(256) void decode_max_kernel(
    const unsigned int* __restrict__ enc, float* __restrict__ xagg)
{
    int idx = blockIdx.x * 256 + threadIdx.x;
    unsigned int e = enc[idx];
    unsigned int b = (e & 0x80000000u) ? (e ^ 0x80000000u) : ~e;
    xagg[idx] = __uint_as_float(b);
}

// ---------------- GIN message aggregation ----------------
__global__ __launch_bounds__(128) void magg_kernel(
    const float* __restrict__ xagg, const int* __restrict__ eig,
    const int* __restrict__ eattr, const float* __restrict__ bemb,
    float* __restrict__ magg)
{
    int e = blockIdx.x, f = threadIdx.x;
    int gr = eig[e], gc = eig[EG + e], bt = eattr[e];
    float v = xagg[gr * HH + f] + bemb[bt * HH + f];
    v = fmaxf(v, 0.f);
    atomicAdd(&magg[gc * HH + f], v);
}

__global__ __launch_bounds__(256) void hg0_kernel(
    const float* __restrict__ xagg, const float* __restrict__ magg,
    const float* __restrict__ eps, float* __restrict__ hg0)
{
    int idx = blockIdx.x * 256 + threadIdx.x;
    hg0[idx] = (1.0f + eps[0]) * xagg[idx] + magg[idx];
}

// ---------------- batchnorm (training-mode batch stats), in-place ----------------
__global__ __launch_bounds__(256) void bn_kernel(
    float* __restrict__ X, const float* __restrict__ gamma,
    const float* __restrict__ beta, int rows, int relu)
{
    int f = blockIdx.x, tid = threadIdx.x;
    float s = 0.f, s2 = 0.f;
    for (int r = tid; r < rows; r += 256) {
        float v = X[(size_t)r * HH + f];
        s += v; s2 += v * v;
    }
    __shared__ float red[256], red2[256];
    red[tid] = s; red2[tid] = s2;
    __syncthreads();
    for (int off = 128; off > 0; off >>= 1) {
        if (tid < off) { red[tid] += red[tid + off]; red2[tid] += red2[tid + off]; }
        __syncthreads();
    }
    __shared__ float smu, sinv;
    if (tid == 0) {
        float mu = red[0] / rows;
        float var = red2[0] / rows - mu * mu;
        smu = mu; sinv = rsqrtf(var + 1e-5f);
    }
    __syncthreads();
    float g = gamma[f], b = beta[f], mu = smu, inv = sinv;
    for (int r = tid; r < rows; r += 256) {
        float v = (X[(size_t)r * HH + f] - mu) * inv * g + b;
        if (relu) v = fmaxf(v, 0.f);
        X[(size_t)r * HH + f] = v;
    }
}

// ---------------- combine branches: x = relu(outb + hg[cnb]) ----------------
__global__ __launch_bounds__(256) void combine_kernel(
    const float* __restrict__ outb, const float* __restrict__ hgB,
    const int* __restrict__ cnb, float* __restrict__ x)
{
    int idx = blockIdx.x * 256 + threadIdx.x;
    int n = idx >> 7, f = idx & 127;
    x[idx] = fmaxf(outb[idx] + hgB[cnb[n] * HH + f], 0.f);
}

// ---------------- pooling (values are >=0 after relu: int-max == float-max) ----------------
__global__ __launch_bounds__(256) void pool1_kernel(
    const float* __restrict__ x, const int* __restrict__ posb, int* __restrict__ p1)
{
    int idx = blockIdx.x * 256 + threadIdx.x;
    int n = idx >> 7, f = idx & 127;
    atomicMax(&p1[posb[n] * HH + f], __float_as_int(x[idx]));
}

__global__ __launch_bounds__(256) void pool2_kernel(
    const int* __restrict__ p1, const int* __restrict__ confb, int* __restrict__ p2)
{
    int idx = blockIdx.x * 256 + threadIdx.x;
    int c = idx >> 7, f = idx & 127;
    atomicMax(&p2[confb[c] * HH + f], p1[idx]);
}

// ---------------- output head: relu(x@W1+b1)@W2+b2 ----------------
__global__ __launch_bounds__(128) void out_layer_kernel(
    const float* __restrict__ xm, const float* __restrict__ w1,
    const float* __restrict__ b1, const float* __restrict__ w2,
    const float* __restrict__ b2, float* __restrict__ out)
{
    int m = blockIdx.x, f = threadIdx.x;
    __shared__ float xs[128];
    xs[f] = xm[m * HH + f];
    __syncthreads();
    float acc = b1[f];
    for (int k = 0; k < 128; k++) acc = fmaf(xs[k], w1[k * HH + f], acc);
    acc = fmaxf(acc, 0.f) * w2[f];
    __shared__ float red[128];
    red[f] = acc;
    __syncthreads();
    for (int off = 64; off > 0; off >>= 1) {
        if (f < off) red[f] += red[f + off];
        __syncthreads();
    }
    if (f == 0) out[m] = red[0] + b2[0];
}

extern "C" void kernel_launch(void* const* d_in, const int* in_sizes, int n_in,
                              void* d_out, int out_size, void* d_ws, size_t ws_size,
                              hipStream_t stream)
{
    const int*   x_topo    = (const int*)d_in[0];
    const float* pos       = (const float*)d_in[1];
    const int*   eic       = (const int*)d_in[2];
    const int*   eig       = (const int*)d_in[3];
    const int*   eattr     = (const int*)d_in[4];
    const int*   cnb       = (const int*)d_in[5];
    const int*   posb      = (const int*)d_in[6];
    const int*   confb     = (const int*)d_in[7];
    const float* atom_emb  = (const float*)d_in[8];
    const float* cf_lin1_w = (const float*)d_in[9];
    const float* cf_mlp_w1 = (const float*)d_in[10];
    const float* cf_mlp_b1 = (const float*)d_in[11];
    const float* cf_mlp_w2 = (const float*)d_in[12];
    const float* cf_mlp_b2 = (const float*)d_in[13];
    const float* cf_lin2_w = (const float*)d_in[14];
    const float* cf_lin2_b = (const float*)d_in[15];
    const float* lin_w     = (const float*)d_in[16];
    const float* lin_b     = (const float*)d_in[17];
    const float* bond_emb  = (const float*)d_in[18];
    const float* gin_w1    = (const float*)d_in[19];
    const float* gin_b1    = (const float*)d_in[20];
    const float* gin_w2    = (const float*)d_in[21];
    const float* gin_b2    = (const float*)d_in[22];
    const float* gin_bn_g  = (const float*)d_in[23];
    const float* gin_bn_b  = (const float*)d_in[24];
    const float* bn_g      = (const float*)d_in[25];
    const float* bn_b      = (const float*)d_in[26];
    const float* gin_eps   = (const float*)d_in[27];
    const float* out_w1    = (const float*)d_in[28];
    const float* out_b1    = (const float*)d_in[29];
    const float* out_w2    = (const float*)d_in[30];
    const float* out_b2    = (const float*)d_in[31];
    float* out = (float*)d_out;

    char* wsb = (char*)d_ws;
    size_t off = 0;
    auto alloc = [&](size_t nfloats) -> float* {
        float* p = (float*)(wsb + off);
        off += nfloats * 4;
        return p;
    };
    float* ew   = alloc(EC);
    float* cwin = alloc(EC);
    float* x    = alloc((size_t)NN * HH);
    float* h1   = alloc((size_t)NN * FF);
    float* agg  = alloc((size_t)NN * FF);
    float* h2   = alloc((size_t)NN * HH);
    float* outb = alloc((size_t)NN * HH);
    unsigned int* enc = (unsigned int*)alloc((size_t)NT * HH);
    float* xagg = alloc((size_t)NT * HH);
    float* magg = alloc((size_t)NT * HH);
    float* hg0  = alloc((size_t)NT * HH);
    float* hgA  = alloc((size_t)NT * HH);
    float* hgB  = alloc((size_t)NT * HH);
    float* p1   = alloc((size_t)NCONF_ * HH);
    float* p2   = alloc((size_t)MM * HH);

    edge_geom_kernel<<<EC / 256, 256, 0, stream>>>(pos, eic, ew, cwin);
    embed_kernel<<<NN * HH / 256, 256, 0, stream>>>(atom_emb, x_topo, cnb, x);

    for (int l = 0; l < 4; l++) {
        // h1 = x @ cf_lin1_w[l]
        gemm_kernel<<<dim3(FF / 64, NN / 64), 256, 0, stream>>>(
            x, cf_lin1_w + (size_t)l * HH * FF, nullptr, nullptr, h1, NN, FF, HH, 0);
        hipMemsetAsync(agg, 0, (size_t)NN * FF * 4, stream);
        edge_mlp_agg_kernel<<<EC / 64, 64, 0, stream>>>(
            ew, cwin, eic,
            cf_mlp_w1 + (size_t)l * GG * FF, cf_mlp_b1 + (size_t)l * FF,
            cf_mlp_w2 + (size_t)l * FF * FF, cf_mlp_b2 + (size_t)l * FF,
            h1, agg);
        // h2 = relu(agg @ cf_lin2_w[l] + b)
        gemm_kernel<<<dim3(HH / 64, NN / 64), 256, 0, stream>>>(
            agg, cf_lin2_w + (size_t)l * FF * HH, cf_lin2_b + (size_t)l * HH,
            nullptr, h2, NN, HH, FF, 1);
        // outb = x + h2 @ lin_w[l] + lin_b[l]
        gemm_kernel<<<dim3(HH / 64, NN / 64), 256, 0, stream>>>(
            h2, lin_w + (size_t)l * HH * HH, lin_b + (size_t)l * HH,
            x, outb, NN, HH, HH, 2);
        // GIN branch on topo graph
        hipMemsetAsync(enc, 0, (size_t)NT * HH * 4, stream);
        encode_max_kernel<<<NN * HH / 256, 256, 0, stream>>>(x, cnb, enc);
        decode_max_kernel<<<NT * HH / 256, 256, 0, stream>>>(enc, xagg);
        hipMemsetAsync(magg, 0, (size_t)NT * HH * 4, stream);
        magg_kernel<<<EG, 128, 0, stream>>>(
            xagg, eig, eattr, bond_emb + (size_t)l * 10 * HH, magg);
        hg0_kernel<<<NT * HH / 256, 256, 0, stream>>>(xagg, magg, gin_eps + l, hg0);
        gemm_kernel<<<dim3(HH / 64, NT / 64), 256, 0, stream>>>(
            hg0, gin_w1 + (size_t)l * HH * HH, gin_b1 + (size_t)l * HH,
            nullptr, hgA, NT, HH, HH, 0);
        bn_kernel<<<HH, 256, 0, stream>>>(
            hgA, gin_bn_g + (size_t)l * HH, gin_bn_b + (size_t)l * HH, NT, 1);
        gemm_kernel<<<dim3(HH / 64, NT / 64), 256, 0, stream>>>(
            hgA, gin_w2 + (size_t)l * HH * HH, gin_b2 + (size_t)l * HH,
            nullptr, hgB, NT, HH, HH, 0);
        bn_kernel<<<HH, 256, 0, stream>>>(
            hgB, bn_g + (size_t)l * HH, bn_b + (size_t)l * HH, NT, 0);
        combine_kernel<<<NN * HH / 256, 256, 0, stream>>>(outb, hgB, cnb, x);
    }

    hipMemsetAsync(p1, 0, (size_t)NCONF_ * HH * 4, stream);
    hipMemsetAsync(p2, 0, (size_t)MM * HH * 4, stream);
    pool1_kernel<<<NN * HH / 256, 256, 0, stream>>>(x, posb, (int*)p1);
    pool2_kernel<<<NCONF_ * HH / 256, 256, 0, stream>>>((const int*)p1, confb, (int*)p2);
    out_layer_kernel<<<MM, 128, 0, stream>>>(p2, out_w1, out_b1, out_w2, out_b2, out);
}

// Round 3
// 2168.241 us; speedup vs baseline: 1.3863x; 1.3863x over previous
//
#include <hip/hip_runtime.h>

#define EC 1048576   // conformer edges
#define NN 65536     // conformer nodes
#define NT 8192      // topo nodes
#define NCONF_ 2048
#define MM 256
#define HH 128
#define FF 64
#define GG 50
#define EG 32768     // graph edges

#define TBL 8192            // Wf table entries
#define TRANGE 14.0f        // Wf(ew) == 0 for ew > ~12 (b1=b2=0, gaussians dead)

constexpr float STEP = 10.0f / 49.0f;
constexpr float GC = -0.5f / (STEP * STEP);

// ---------------- edge geometry: ew only (cwin folded into table) ----------------
__global__ __launch_bounds__(256) void edge_geom_kernel(
    const float* __restrict__ pos, const int* __restrict__ ei,
    float* __restrict__ ew)
{
    int e = blockIdx.x * 256 + threadIdx.x;
    int r = ei[e], c = ei[EC + e];
    float dx = pos[r*3+0] - pos[c*3+0];
    float dy = pos[r*3+1] - pos[c*3+1];
    float dz = pos[r*3+2] - pos[c*3+2];
    ew[e] = sqrtf(dx*dx + dy*dy + dz*dz + 1e-12f);
}

// ---------------- atom embedding broadcast ----------------
__global__ __launch_bounds__(256) void embed_kernel(
    const float* __restrict__ emb, const int* __restrict__ xtopo,
    const int* __restrict__ cnb, float* __restrict__ x)
{
    int idx = blockIdx.x * 256 + threadIdx.x;
    int n = idx >> 7, f = idx & 127;
    x[idx] = emb[xtopo[cnb[n]] * HH + f];
}

// ---------------- CSR build: histogram / scan / scatter ----------------
__global__ __launch_bounds__(256) void hist_kernel(
    const int* __restrict__ eic, int* __restrict__ deg)
{
    int e = blockIdx.x * 256 + threadIdx.x;
    atomicAdd(&deg[eic[EC + e]], 1);
}

__global__ __launch_bounds__(256) void scan1_kernel(
    const int* __restrict__ deg, int* __restrict__ offs, int* __restrict__ bsum)
{
    __shared__ int s[256];
    int tid = threadIdx.x, b = blockIdx.x;
    int v = deg[b * 256 + tid];
    s[tid] = v;
    __syncthreads();
    for (int off = 1; off < 256; off <<= 1) {
        int t = (tid >= off) ? s[tid - off] : 0;
        __syncthreads();
        s[tid] += t;
        __syncthreads();
    }
    offs[b * 256 + tid] = s[tid] - v;     // exclusive within block
    if (tid == 255) bsum[b] = s[255];
}

__global__ __launch_bounds__(256) void scan2_kernel(
    const int* __restrict__ bsum, int* __restrict__ boff)
{
    __shared__ int s[256];
    int tid = threadIdx.x;
    int v = bsum[tid];
    s[tid] = v;
    __syncthreads();
    for (int off = 1; off < 256; off <<= 1) {
        int t = (tid >= off) ? s[tid - off] : 0;
        __syncthreads();
        s[tid] += t;
        __syncthreads();
    }
    boff[tid] = s[tid] - v;
}

__global__ __launch_bounds__(256) void scan3_kernel(
    int* __restrict__ offs, const int* __restrict__ boff, int* __restrict__ cursor)
{
    int i = blockIdx.x * 256 + threadIdx.x;
    int v = offs[i] + boff[i >> 8];
    offs[i] = v;
    cursor[i] = v;
    if (i == 0) offs[NN] = EC;
}

__global__ __launch_bounds__(256) void scatter_kernel(
    const int* __restrict__ eic, int* __restrict__ cursor, int* __restrict__ csr)
{
    int e = blockIdx.x * 256 + threadIdx.x;
    int c = eic[EC + e];
    int p = atomicAdd(&cursor[c], 1);
    csr[p] = e;
}

// ---------------- per-layer Wf table: table[p][j] = (relu(ea@W1)@W2 + b2)_j * cwin ----------------
__global__ __launch_bounds__(64) void build_table_kernel(
    const float* __restrict__ w1, const float* __restrict__ b1,
    const float* __restrict__ w2, const float* __restrict__ b2,
    float* __restrict__ table)
{
    int p = blockIdx.x, lane = threadIdx.x;
    float w = p * (TRANGE / (TBL - 1));
    float t = b1[lane];
    for (int g = 0; g < GG; g++) {
        float d = w - g * STEP;
        float ea = __expf(GC * d * d);
        t = fmaf(ea, w1[g * 64 + lane], t);
    }
    __shared__ float ts[64];
    ts[lane] = fmaxf(t, 0.f);
    __syncthreads();
    float wf = b2[lane];
    for (int i = 0; i < 64; i++)
        wf = fmaf(ts[i], w2[i * 64 + lane], wf);
    float cw = 0.5f * (__cosf(w * (3.14159265358979323846f / 10.0f)) + 1.0f);
    table[p * 64 + lane] = wf * cw;
}

// ---------------- CSR edge aggregation: wave per node, lane = feature ----------------
__global__ __launch_bounds__(256) void edge_agg_csr_kernel(
    const int* __restrict__ offs, const int* __restrict__ csr,
    const int* __restrict__ eic, const float* __restrict__ ew,
    const float* __restrict__ table, const float* __restrict__ h1,
    float* __restrict__ agg)
{
    int node = (blockIdx.x * 256 + threadIdx.x) >> 6;
    int lane = threadIdx.x & 63;
    int beg = offs[node], end = offs[node + 1];
    const float SCALE = (TBL - 1) / TRANGE;
    float acc = 0.f;
    for (int p = beg; p < end; p++) {
        int e = csr[p];
        int r = eic[e];
        float w = ew[e];
        float u = w * SCALE;
        int i0 = (int)u;
        if (i0 >= TBL - 1) continue;     // Wf == 0 beyond range (wave-uniform)
        float fr = u - (float)i0;
        float t0 = table[i0 * 64 + lane];
        float t1 = table[i0 * 64 + 64 + lane];
        float wf = fmaf(t1 - t0, fr, t0);
        acc = fmaf(h1[(size_t)r * 64 + lane], wf, acc);
    }
    agg[(size_t)node * 64 + lane] = acc;
}

// ---------------- generic fp32 GEMM: C = A[MxK] @ B[KxN] (+bias)(+res)(relu) ----------------
__global__ __launch_bounds__(256) void gemm_kernel(
    const float* __restrict__ A, const float* __restrict__ B,
    const float* __restrict__ bias, const float* __restrict__ res,
    float* __restrict__ C, int M, int N, int K, int flags)
{
    __shared__ float As[16][68];
    __shared__ float Bs[16][68];
    int tid = threadIdx.x;
    int m0 = blockIdx.y * 64, n0 = blockIdx.x * 64;
    int la_m = tid >> 2;
    int la_k = (tid & 3) * 4;
    int lb_k = tid >> 4;
    int lb_n = (tid & 15) * 4;
    int tx = tid & 15, ty = tid >> 4;
    float acc[4][4] = {};
    const float* Ap = A + (size_t)(m0 + la_m) * K + la_k;
    const float* Bp = B + (size_t)lb_k * N + n0 + lb_n;
    for (int k0 = 0; k0 < K; k0 += 16) {
        float4 av = *(const float4*)(Ap + k0);
        float4 bv = *(const float4*)(Bp + (size_t)k0 * N);
        __syncthreads();
        As[la_k+0][la_m] = av.x; As[la_k+1][la_m] = av.y;
        As[la_k+2][la_m] = av.z; As[la_k+3][la_m] = av.w;
        *(float4*)&Bs[lb_k][lb_n] = bv;
        __syncthreads();
        #pragma unroll
        for (int kk = 0; kk < 16; kk++) {
            float4 a = *(const float4*)&As[kk][ty*4];
            float4 b = *(const float4*)&Bs[kk][tx*4];
            float ar[4] = {a.x, a.y, a.z, a.w};
            float br[4] = {b.x, b.y, b.z, b.w};
            #pragma unroll
            for (int i = 0; i < 4; i++)
                #pragma unroll
                for (int j = 0; j < 4; j++)
                    acc[i][j] = fmaf(ar[i], br[j], acc[i][j]);
        }
    }
    #pragma unroll
    for (int i = 0; i < 4; i++) {
        int row = m0 + ty*4 + i;
        #pragma unroll
        for (int j = 0; j < 4; j++) {
            int col = n0 + tx*4 + j;
            float v = acc[i][j];
            if (bias) v += bias[col];
            if (flags & 2) v += res[(size_t)row * N + col];
            if (flags & 1) v = fmaxf(v, 0.f);
            C[(size_t)row * N + col] = v;
        }
    }
}

// ---------------- segment_max via order-preserving uint encoding ----------------
__global__ __launch_bounds__(256) void encode_max_kernel(
    const float* __restrict__ x, const int* __restrict__ cnb,
    unsigned int* __restrict__ enc)
{
    int idx = blockIdx.x * 256 + threadIdx.x;
    int n = idx >> 7, f = idx & 127;
    unsigned int b = __float_as_uint(x[idx]);
    unsigned int e = (b & 0x80000000u) ? ~b : (b | 0x80000000u);
    atomicMax(&enc[cnb[n] * HH + f], e);
}

__global__ __launch_bounds__(256) void decode_max_kernel(
    const unsigned int* __restrict__ enc, float* __restrict__ xagg)
{
    int idx = blockIdx.x * 256 + threadIdx.x;
    unsigned int e = enc[idx];
    unsigned int b = (e & 0x80000000u) ? (e ^ 0x80000000u) : ~e;
    xagg[idx] = __uint_as_float(b);
}

// ---------------- GIN message aggregation ----------------
__global__ __launch_bounds__(128) void magg_kernel(
    const float* __restrict__ xagg, const int* __restrict__ eig,
    const int* __restrict__ eattr, const float* __restrict__ bemb,
    float* __restrict__ magg)
{
    int e = blockIdx.x, f = threadIdx.x;
    int gr = eig[e], gc = eig[EG + e], bt = eattr[e];
    float v = xagg[gr * HH + f] + bemb[bt * HH + f];
    v = fmaxf(v, 0.f);
    atomicAdd(&magg[gc * HH + f], v);
}

__global__ __launch_bounds__(256) void hg0_kernel(
    const float* __restrict__ xagg, const float* __restrict__ magg,
    const float* __restrict__ eps, float* __restrict__ hg0)
{
    int idx = blockIdx.x * 256 + threadIdx.x;
    hg0[idx] = (1.0f + eps[0]) * xagg[idx] + magg[idx];
}

// ---------------- batchnorm (training-mode batch stats), in-place ----------------
__global__ __launch_bounds__(256) void bn_kernel(
    float* __restrict__ X, const float* __restrict__ gamma,
    const float* __restrict__ beta, int rows, int relu)
{
    int f = blockIdx.x, tid = threadIdx.x;
    float s = 0.f, s2 = 0.f;
    for (int r = tid; r < rows; r += 256) {
        float v = X[(size_t)r * HH + f];
        s += v; s2 += v * v;
    }
    __shared__ float red[256], red2[256];
    red[tid] = s; red2[tid] = s2;
    __syncthreads();
    for (int off = 128; off > 0; off >>= 1) {
        if (tid < off) { red[tid] += red[tid + off]; red2[tid] += red2[tid + off]; }
        __syncthreads();
    }
    __shared__ float smu, sinv;
    if (tid == 0) {
        float mu = red[0] / rows;
        float var = red2[0] / rows - mu * mu;
        smu = mu; sinv = rsqrtf(var + 1e-5f);
    }
    __syncthreads();
    float g = gamma[f], b = beta[f], mu = smu, inv = sinv;
    for (int r = tid; r < rows; r += 256) {
        float v = (X[(size_t)r * HH + f] - mu) * inv * g + b;
        if (relu) v = fmaxf(v, 0.f);
        X[(size_t)r * HH + f] = v;
    }
}

// ---------------- combine branches: x = relu(outb + hg[cnb]) ----------------
__global__ __launch_bounds__(256) void combine_kernel(
    const float* __restrict__ outb, const float* __restrict__ hgB,
    const int* __restrict__ cnb, float* __restrict__ x)
{
    int idx = blockIdx.x * 256 + threadIdx.x;
    int n = idx >> 7, f = idx & 127;
    x[idx] = fmaxf(outb[idx] + hgB[cnb[n] * HH + f], 0.f);
}

// ---------------- pooling ----------------
__global__ __launch_bounds__(256) void pool1_kernel(
    const float* __restrict__ x, const int* __restrict__ posb, int* __restrict__ p1)
{
    int idx = blockIdx.x * 256 + threadIdx.x;
    int n = idx >> 7, f = idx & 127;
    atomicMax(&p1[posb[n] * HH + f], __float_as_int(x[idx]));
}

__global__ __launch_bounds__(256) void pool2_kernel(
    const int* __restrict__ p1, const int* __restrict__ confb, int* __restrict__ p2)
{
    int idx = blockIdx.x * 256 + threadIdx.x;
    int c = idx >> 7, f = idx & 127;
    atomicMax(&p2[confb[c] * HH + f], p1[idx]);
}

// ---------------- output head ----------------
__global__ __launch_bounds__(128) void out_layer_kernel(
    const float* __restrict__ xm, const float* __restrict__ w1,
    const float* __restrict__ b1, const float* __restrict__ w2,
    const float* __restrict__ b2, float* __restrict__ out)
{
    int m = blockIdx.x, f = threadIdx.x;
    __shared__ float xs[128];
    xs[f] = xm[m * HH + f];
    __syncthreads();
    float acc = b1[f];
    for (int k = 0; k < 128; k++) acc = fmaf(xs[k], w1[k * HH + f], acc);
    acc = fmaxf(acc, 0.f) * w2[f];
    __shared__ float red[128];
    red[f] = acc;
    __syncthreads();
    for (int off = 64; off > 0; off >>= 1) {
        if (f < off) red[f] += red[f + off];
        __syncthreads();
    }
    if (f == 0) out[m] = red[0] + b2[0];
}

extern "C" void kernel_launch(void* const* d_in, const int* in_sizes, int n_in,
                              void* d_out, int out_size, void* d_ws, size_t ws_size,
                              hipStream_t stream)
{
    const int*   x_topo    = (const int*)d_in[0];
    const float* pos       = (const float*)d_in[1];
    const int*   eic       = (const int*)d_in[2];
    const int*   eig       = (const int*)d_in[3];
    const int*   eattr     = (const int*)d_in[4];
    const int*   cnb       = (const int*)d_in[5];
    const int*   posb      = (const int*)d_in[6];
    const int*   confb     = (const int*)d_in[7];
    const float* atom_emb  = (const float*)d_in[8];
    const float* cf_lin1_w = (const float*)d_in[9];
    const float* cf_mlp_w1 = (const float*)d_in[10];
    const float* cf_mlp_b1 = (const float*)d_in[11];
    const float* cf_mlp_w2 = (const float*)d_in[12];
    const float* cf_mlp_b2 = (const float*)d_in[13];
    const float* cf_lin2_w = (const float*)d_in[14];
    const float* cf_lin2_b = (const float*)d_in[15];
    const float* lin_w     = (const float*)d_in[16];
    const float* lin_b     = (const float*)d_in[17];
    const float* bond_emb  = (const float*)d_in[18];
    const float* gin_w1    = (const float*)d_in[19];
    const float* gin_b1    = (const float*)d_in[20];
    const float* gin_w2    = (const float*)d_in[21];
    const float* gin_b2    = (const float*)d_in[22];
    const float* gin_bn_g  = (const float*)d_in[23];
    const float* gin_bn_b  = (const float*)d_in[24];
    const float* bn_g      = (const float*)d_in[25];
    const float* bn_b      = (const float*)d_in[26];
    const float* gin_eps   = (const float*)d_in[27];
    const float* out_w1    = (const float*)d_in[28];
    const float* out_b1    = (const float*)d_in[29];
    const float* out_w2    = (const float*)d_in[30];
    const float* out_b2    = (const float*)d_in[31];
    float* out = (float*)d_out;

    char* wsb = (char*)d_ws;
    size_t off = 0;
    auto alloc = [&](size_t nfloats) -> float* {
        float* p = (float*)(wsb + off);
        off += nfloats * 4;
        return p;
    };
    float* ew    = alloc(EC);
    float* x     = alloc((size_t)NN * HH);
    float* h1    = alloc((size_t)NN * FF);
    float* agg   = alloc((size_t)NN * FF);
    float* h2    = alloc((size_t)NN * HH);
    float* outb  = alloc((size_t)NN * HH);
    unsigned int* enc = (unsigned int*)alloc((size_t)NT * HH);
    float* xagg  = alloc((size_t)NT * HH);
    float* magg  = alloc((size_t)NT * HH);
    float* hg0   = alloc((size_t)NT * HH);
    float* hgA   = alloc((size_t)NT * HH);
    float* hgB   = alloc((size_t)NT * HH);
    float* p1    = alloc((size_t)NCONF_ * HH);
    float* p2    = alloc((size_t)MM * HH);
    float* table = alloc((size_t)TBL * 64);
    int* deg     = (int*)alloc(NN);
    int* offs    = (int*)alloc(NN + 1);
    int* cursor  = (int*)alloc(NN);
    int* bsum    = (int*)alloc(256);
    int* boff    = (int*)alloc(256);
    int* csr     = (int*)alloc(EC);

    // --- geometry + embedding ---
    edge_geom_kernel<<<EC / 256, 256, 0, stream>>>(pos, eic, ew);
    embed_kernel<<<NN * HH / 256, 256, 0, stream>>>(atom_emb, x_topo, cnb, x);

    // --- CSR by destination (once; reused by all 4 layers) ---
    hipMemsetAsync(deg, 0, NN * 4, stream);
    hist_kernel<<<EC / 256, 256, 0, stream>>>(eic, deg);
    scan1_kernel<<<NN / 256, 256, 0, stream>>>(deg, offs, bsum);
    scan2_kernel<<<1, 256, 0, stream>>>(bsum, boff);
    scan3_kernel<<<NN / 256, 256, 0, stream>>>(offs, boff, cursor);
    scatter_kernel<<<EC / 256, 256, 0, stream>>>(eic, cursor, csr);

    for (int l = 0; l < 4; l++) {
        // Wf(ew) table for this layer (includes cosine window)
        build_table_kernel<<<TBL, 64, 0, stream>>>(
            cf_mlp_w1 + (size_t)l * GG * FF, cf_mlp_b1 + (size_t)l * FF,
            cf_mlp_w2 + (size_t)l * FF * FF, cf_mlp_b2 + (size_t)l * FF, table);
        // h1 = x @ cf_lin1_w[l]
        gemm_kernel<<<dim3(FF / 64, NN / 64), 256, 0, stream>>>(
            x, cf_lin1_w + (size_t)l * HH * FF, nullptr, nullptr, h1, NN, FF, HH, 0);
        // agg[c] = sum_e h1[row_e] * Wf(ew_e)   (CSR, no atomics)
        edge_agg_csr_kernel<<<NN * 64 / 256, 256, 0, stream>>>(
            offs, csr, eic, ew, table, h1, agg);
        // h2 = relu(agg @ cf_lin2_w[l] + b)
        gemm_kernel<<<dim3(HH / 64, NN / 64), 256, 0, stream>>>(
            agg, cf_lin2_w + (size_t)l * FF * HH, cf_lin2_b + (size_t)l * HH,
            nullptr, h2, NN, HH, FF, 1);
        // outb = x + h2 @ lin_w[l] + lin_b[l]
        gemm_kernel<<<dim3(HH / 64, NN / 64), 256, 0, stream>>>(
            h2, lin_w + (size_t)l * HH * HH, lin_b + (size_t)l * HH,
            x, outb, NN, HH, HH, 2);
        // GIN branch on topo graph
        hipMemsetAsync(enc, 0, (size_t)NT * HH * 4, stream);
        encode_max_kernel<<<NN * HH / 256, 256, 0, stream>>>(x, cnb, enc);
        decode_max_kernel<<<NT * HH / 256, 256, 0, stream>>>(enc, xagg);
        hipMemsetAsync(magg, 0, (size_t)NT * HH * 4, stream);
        magg_kernel<<<EG, 128, 0, stream>>>(
            xagg, eig, eattr, bond_emb + (size_t)l * 10 * HH, magg);
        hg0_kernel<<<NT * HH / 256, 256, 0, stream>>>(xagg, magg, gin_eps + l, hg0);
        gemm_kernel<<<dim3(HH / 64, NT / 64), 256, 0, stream>>>(
            hg0, gin_w1 + (size_t)l * HH * HH, gin_b1 + (size_t)l * HH,
            nullptr, hgA, NT, HH, HH, 0);
        bn_kernel<<<HH, 256, 0, stream>>>(
            hgA, gin_bn_g + (size_t)l * HH, gin_bn_b + (size_t)l * HH, NT, 1);
        gemm_kernel<<<dim3(HH / 64, NT / 64), 256, 0, stream>>>(
            hgA, gin_w2 + (size_t)l * HH * HH, gin_b2 + (size_t)l * HH,
            nullptr, hgB, NT, HH, HH, 0);
        bn_kernel<<<HH, 256, 0, stream>>>(
            hgB, bn_g + (size_t)l * HH, bn_b + (size_t)l * HH, NT, 0);
        combine_kernel<<<NN * HH / 256, 256, 0, stream>>>(outb, hgB, cnb, x);
    }

    hipMemsetAsync(p1, 0, (size_t)NCONF_ * HH * 4, stream);
    hipMemsetAsync(p2, 0, (size_t)MM * HH * 4, stream);
    pool1_kernel<<<NN * HH / 256, 256, 0, stream>>>(x, posb, (int*)p1);
    pool2_kernel<<<NCONF_ * HH / 256, 256, 0, stream>>>((const int*)p1, confb, (int*)p2);
    out_layer_kernel<<<MM, 128, 0, stream>>>(p2, out_w1, out_b1, out_w2, out_b2, out);
}

// Round 5
// 1768.195 us; speedup vs baseline: 1.6999x; 1.2262x over previous
//
#include <hip/hip_runtime.h>
#include <hip/hip_bf16.h>

#define EC 1048576   // conformer edges
#define NN 65536     // conformer nodes
#define NT 8192      // topo nodes
#define NCONF_ 2048
#define MM 256
#define HH 128
#define FF 64
#define GG 50
#define EG 32768     // graph edges

#define TBL 8192            // Wf table entries
#define TRANGE 14.0f        // Wf(ew) == 0 beyond (b1=b2=0, gaussians dead)

constexpr float STEP = 10.0f / 49.0f;
constexpr float GC = -0.5f / (STEP * STEP);

typedef __attribute__((ext_vector_type(8))) short bf16x8;
typedef __attribute__((ext_vector_type(4))) float f32x4;

__device__ __forceinline__ ushort f2b(float v) {
    __hip_bfloat16 h = __float2bfloat16(v);
    return *(ushort*)&h;
}
__device__ __forceinline__ float b2f(ushort u) {
    return __uint_as_float(((unsigned)u) << 16);
}

// ---------------- edge geometry ----------------
__global__ __launch_bounds__(256) void edge_geom_kernel(
    const float* __restrict__ pos, const int* __restrict__ ei,
    float* __restrict__ ew)
{
    int e = blockIdx.x * 256 + threadIdx.x;
    int r = ei[e], c = ei[EC + e];
    float dx = pos[r*3+0] - pos[c*3+0];
    float dy = pos[r*3+1] - pos[c*3+1];
    float dz = pos[r*3+2] - pos[c*3+2];
    ew[e] = sqrtf(dx*dx + dy*dy + dz*dz + 1e-12f);
}

// ---------------- atom embedding broadcast (fp32 + bf16 copies) ----------------
__global__ __launch_bounds__(256) void embed_kernel(
    const float* __restrict__ emb, const int* __restrict__ xtopo,
    const int* __restrict__ cnb, float* __restrict__ x, ushort* __restrict__ xb)
{
    int idx = blockIdx.x * 256 + threadIdx.x;
    int n = idx >> 7, f = idx & 127;
    float v = emb[xtopo[cnb[n]] * HH + f];
    x[idx] = v;
    xb[idx] = f2b(v);
}

// ---------------- CSR build ----------------
__global__ __launch_bounds__(256) void hist_kernel(
    const int* __restrict__ eic, int* __restrict__ deg)
{
    int e = blockIdx.x * 256 + threadIdx.x;
    atomicAdd(&deg[eic[EC + e]], 1);
}

__global__ __launch_bounds__(256) void scan1_kernel(
    const int* __restrict__ deg, int* __restrict__ offs, int* __restrict__ bsum)
{
    __shared__ int s[256];
    int tid = threadIdx.x, b = blockIdx.x;
    int v = deg[b * 256 + tid];
    s[tid] = v;
    __syncthreads();
    for (int off = 1; off < 256; off <<= 1) {
        int t = (tid >= off) ? s[tid - off] : 0;
        __syncthreads();
        s[tid] += t;
        __syncthreads();
    }
    offs[b * 256 + tid] = s[tid] - v;
    if (tid == 255) bsum[b] = s[255];
}

__global__ __launch_bounds__(256) void scan2_kernel(
    const int* __restrict__ bsum, int* __restrict__ boff)
{
    __shared__ int s[256];
    int tid = threadIdx.x;
    int v = bsum[tid];
    s[tid] = v;
    __syncthreads();
    for (int off = 1; off < 256; off <<= 1) {
        int t = (tid >= off) ? s[tid - off] : 0;
        __syncthreads();
        s[tid] += t;
        __syncthreads();
    }
    boff[tid] = s[tid] - v;
}

__global__ __launch_bounds__(256) void scan3_kernel(
    int* __restrict__ offs, const int* __restrict__ boff, int* __restrict__ cursor)
{
    int i = blockIdx.x * 256 + threadIdx.x;
    int v = offs[i] + boff[i >> 8];
    offs[i] = v;
    cursor[i] = v;
    if (i == 0) offs[NN] = EC;
}

// scatter + permute edge payload into CSR order (src index, pre-scaled distance)
__global__ __launch_bounds__(256) void scatter_kernel(
    const int* __restrict__ eic, const float* __restrict__ ew,
    int* __restrict__ cursor, int* __restrict__ src_csr, float* __restrict__ u_csr)
{
    int e = blockIdx.x * 256 + threadIdx.x;
    int c = eic[EC + e];
    int p = atomicAdd(&cursor[c], 1);
    src_csr[p] = eic[e];
    u_csr[p] = ew[e] * ((TBL - 1) / TRANGE);
}

// ---------------- per-layer Wf table ----------------
__global__ __launch_bounds__(64) void build_table_kernel(
    const float* __restrict__ w1, const float* __restrict__ b1,
    const float* __restrict__ w2, const float* __restrict__ b2,
    float* __restrict__ table)
{
    int p = blockIdx.x, lane = threadIdx.x;
    float w = p * (TRANGE / (TBL - 1));
    float t = b1[lane];
    for (int g = 0; g < GG; g++) {
        float d = w - g * STEP;
        float ea = __expf(GC * d * d);
        t = fmaf(ea, w1[g * 64 + lane], t);
    }
    __shared__ float ts[64];
    ts[lane] = fmaxf(t, 0.f);
    __syncthreads();
    float wf = b2[lane];
    for (int i = 0; i < 64; i++)
        wf = fmaf(ts[i], w2[i * 64 + lane], wf);
    float cw = 0.5f * (__cosf(w * (3.14159265358979323846f / 10.0f)) + 1.0f);
    table[p * 64 + lane] = wf * cw;
}

// ---------------- weight prep: fp32 KxN -> bf16 MFMA-fragment order ----------------
// Wf[((nt*KTl + kt)*64 + lane)*8 + j] = W[kt*32 + (lane>>4)*8 + j][nt*16 + (lane&15)]
__global__ __launch_bounds__(256) void prep_w_kernel(
    const float* __restrict__ W, ushort* __restrict__ Wf, int K, int N)
{
    int t = blockIdx.x * 256 + threadIdx.x;   // N*K total
    int j = t & 7;
    int lane = (t >> 3) & 63;
    int rest = t >> 9;
    int KTl = K >> 5;
    int kt = rest % KTl;
    int nt = rest / KTl;
    int k = kt * 32 + (lane >> 4) * 8 + j;
    int n = nt * 16 + (lane & 15);
    Wf[t] = f2b(W[(size_t)k * N + n]);
}

// ---------------- bf16 MFMA GEMM: C = A[MxK] @ B[KxN] (+bias)(+res fp32)(relu) ----------------
// A: bf16 row-major. Bf: fragment-ordered bf16. Outputs: Cb (bf16) and/or Cf (fp32).
__global__ __launch_bounds__(256) void gemm_bf16_kernel(
    const ushort* __restrict__ A, const ushort* __restrict__ Bf,
    const float* __restrict__ bias, const float* __restrict__ res,
    ushort* __restrict__ Cb, float* __restrict__ Cf,
    int M, int N, int K, int relu)
{
    int tid = threadIdx.x;
    int wave = tid >> 6, lane = tid & 63;
    int m0 = (blockIdx.x * 4 + wave) * 16;
    int ntile = N >> 4, ktile = K >> 5;
    int arow = m0 + (lane & 15);
    int ak = (lane >> 4) * 8;
    f32x4 acc[8];
    #pragma unroll
    for (int i = 0; i < 8; i++) acc[i] = (f32x4){0.f, 0.f, 0.f, 0.f};
    for (int kt = 0; kt < ktile; kt++) {
        bf16x8 a = *(const bf16x8*)(A + (size_t)arow * K + kt * 32 + ak);
        const ushort* bp = Bf + ((size_t)kt * 64 + lane) * 8;
        for (int nt = 0; nt < ntile; nt++) {
            bf16x8 b = *(const bf16x8*)(bp + (size_t)nt * ktile * 512);
            acc[nt] = __builtin_amdgcn_mfma_f32_16x16x32_bf16(a, b, acc[nt], 0, 0, 0);
        }
    }
    int col0 = lane & 15;
    int rbase = m0 + (lane >> 4) * 4;
    for (int nt = 0; nt < ntile; nt++) {
        int col = nt * 16 + col0;
        float bs = bias ? bias[col] : 0.f;
        #pragma unroll
        for (int r = 0; r < 4; r++) {
            int row = rbase + r;
            float v = acc[nt][r] + bs;
            if (res) v += res[(size_t)row * N + col];
            if (relu) v = fmaxf(v, 0.f);
            if (Cf) Cf[(size_t)row * N + col] = v;
            if (Cb) Cb[(size_t)row * N + col] = f2b(v);
        }
    }
}

// ---------------- CSR edge aggregation: wave per node, lane = feature ----------------
__global__ __launch_bounds__(256) void edge_agg_csr_kernel(
    const int* __restrict__ offs, const int* __restrict__ src_csr,
    const float* __restrict__ u_csr, const float* __restrict__ table,
    const ushort* __restrict__ h1b, ushort* __restrict__ aggb)
{
    int node = (blockIdx.x * 256 + threadIdx.x) >> 6;
    int lane = threadIdx.x & 63;
    int beg = offs[node], end = offs[node + 1];
    float acc = 0.f;
    for (int p = beg; p < end; p++) {
        float u = u_csr[p];
        int i0 = (int)u;
        if (i0 >= TBL - 1) continue;     // Wf == 0 beyond range (wave-uniform)
        int r = src_csr[p];
        float fr = u - (float)i0;
        float t0 = table[i0 * 64 + lane];
        float t1 = table[i0 * 64 + 64 + lane];
        float wf = fmaf(t1 - t0, fr, t0);
        acc = fmaf(b2f(h1b[(size_t)r * 64 + lane]), wf, acc);
    }
    aggb[(size_t)node * 64 + lane] = f2b(acc);
}

// ---------------- generic fp32 GEMM (GIN branch, small) ----------------
__global__ __launch_bounds__(256) void gemm_kernel(
    const float* __restrict__ A, const float* __restrict__ B,
    const float* __restrict__ bias, const float* __restrict__ res,
    float* __restrict__ C, int M, int N, int K, int flags)
{
    __shared__ float As[16][68];
    __shared__ float Bs[16][68];
    int tid = threadIdx.x;
    int m0 = blockIdx.y * 64, n0 = blockIdx.x * 64;
    int la_m = tid >> 2;
    int la_k = (tid & 3) * 4;
    int lb_k = tid >> 4;
    int lb_n = (tid & 15) * 4;
    int tx = tid & 15, ty = tid >> 4;
    float acc[4][4] = {};
    const float* Ap = A + (size_t)(m0 + la_m) * K + la_k;
    const float* Bp = B + (size_t)lb_k * N + n0 + lb_n;
    for (int k0 = 0; k0 < K; k0 += 16) {
        float4 av = *(const float4*)(Ap + k0);
        float4 bv = *(const float4*)(Bp + (size_t)k0 * N);
        __syncthreads();
        As[la_k+0][la_m] = av.x; As[la_k+1][la_m] = av.y;
        As[la_k+2][la_m] = av.z; As[la_k+3][la_m] = av.w;
        *(float4*)&Bs[lb_k][lb_n] = bv;
        __syncthreads();
        #pragma unroll
        for (int kk = 0; kk < 16; kk++) {
            float4 a = *(const float4*)&As[kk][ty*4];
            float4 b = *(const float4*)&Bs[kk][tx*4];
            float ar[4] = {a.x, a.y, a.z, a.w};
            float br[4] = {b.x, b.y, b.z, b.w};
            #pragma unroll
            for (int i = 0; i < 4; i++)
                #pragma unroll
                for (int j = 0; j < 4; j++)
                    acc[i][j] = fmaf(ar[i], br[j], acc[i][j]);
        }
    }
    #pragma unroll
    for (int i = 0; i < 4; i++) {
        int row = m0 + ty*4 + i;
        #pragma unroll
        for (int j = 0; j < 4; j++) {
            int col = n0 + tx*4 + j;
            float v = acc[i][j];
            if (bias) v += bias[col];
            if (flags & 2) v += res[(size_t)row * N + col];
            if (flags & 1) v = fmaxf(v, 0.f);
            C[(size_t)row * N + col] = v;
        }
    }
}

// ---------------- segment_max via order-preserving uint encoding ----------------
__global__ __launch_bounds__(256) void encode_max_kernel(
    const float* __restrict__ x, const int* __restrict__ cnb,
    unsigned int* __restrict__ enc)
{
    int idx = blockIdx.x * 256 + threadIdx.x;
    int n = idx >> 7, f = idx & 127;
    unsigned int b = __float_as_uint(x[idx]);
    unsigned int e = (b & 0x80000000u) ? ~b : (b | 0x80000000u);
    atomicMax(&enc[cnb[n] * HH + f], e);
}

__global__ __launch_bounds__(256) void decode_max_kernel(
    const unsigned int* __restrict__ enc, float* __restrict__ xagg)
{
    int idx = blockIdx.x * 256 + threadIdx.x;
    unsigned int e = enc[idx];
    unsigned int b = (e & 0x80000000u) ? (e ^ 0x80000000u) : ~e;
    xagg[idx] = __uint_as_float(b);
}

// ---------------- GIN message aggregation ----------------
__global__ __launch_bounds__(128) void magg_kernel(
    const float* __restrict__ xagg, const int* __restrict__ eig,
    const int* __restrict__ eattr, const float* __restrict__ bemb,
    float* __restrict__ magg)
{
    int e = blockIdx.x, f = threadIdx.x;
    int gr = eig[e], gc = eig[EG + e], bt = eattr[e];
    float v = xagg[gr * HH + f] + bemb[bt * HH + f];
    v = fmaxf(v, 0.f);
    atomicAdd(&magg[gc * HH + f], v);
}

__global__ __launch_bounds__(256) void hg0_kernel(
    const float* __restrict__ xagg, const float* __restrict__ magg,
    const float* __restrict__ eps, float* __restrict__ hg0)
{
    int idx = blockIdx.x * 256 + threadIdx.x;
    hg0[idx] = (1.0f + eps[0]) * xagg[idx] + magg[idx];
}

// ---------------- batchnorm (training-mode batch stats), in-place ----------------
__global__ __launch_bounds__(256) void bn_kernel(
    float* __restrict__ X, const float* __restrict__ gamma,
    const float* __restrict__ beta, int rows, int relu)
{
    int f = blockIdx.x, tid = threadIdx.x;
    float s = 0.f, s2 = 0.f;
    for (int r = tid; r < rows; r += 256) {
        float v = X[(size_t)r * HH + f];
        s += v; s2 += v * v;
    }
    __shared__ float red[256], red2[256];
    red[tid] = s; red2[tid] = s2;
    __syncthreads();
    for (int off = 128; off > 0; off >>= 1) {
        if (tid < off) { red[tid] += red[tid + off]; red2[tid] += red2[tid + off]; }
        __syncthreads();
    }
    __shared__ float smu, sinv;
    if (tid == 0) {
        float mu = red[0] / rows;
        float var = red2[0] / rows - mu * mu;
        smu = mu; sinv = rsqrtf(var + 1e-5f);
    }
    __syncthreads();
    float g = gamma[f], b = beta[f], mu = smu, inv = sinv;
    for (int r = tid; r < rows; r += 256) {
        float v = (X[(size_t)r * HH + f] - mu) * inv * g + b;
        if (relu) v = fmaxf(v, 0.f);
        X[(size_t)r * HH + f] = v;
    }
}

// ---------------- combine: x = relu(outb + hg[cnb]) (fp32 + bf16 copies) ----------------
__global__ __launch_bounds__(256) void combine_kernel(
    const float* __restrict__ outb, const float* __restrict__ hgB,
    const int* __restrict__ cnb, float* __restrict__ x, ushort* __restrict__ xb)
{
    int idx = blockIdx.x * 256 + threadIdx.x;
    int n = idx >> 7, f = idx & 127;
    float v = fmaxf(outb[idx] + hgB[cnb[n] * HH + f], 0.f);
    x[idx] = v;
    xb[idx] = f2b(v);
}

// ---------------- pooling ----------------
__global__ __launch_bounds__(256) void pool1_kernel(
    const float* __restrict__ x, const int* __restrict__ posb, int* __restrict__ p1)
{
    int idx = blockIdx.x * 256 + threadIdx.x;
    int n = idx >> 7, f = idx & 127;
    atomicMax(&p1[posb[n] * HH + f], __float_as_int(x[idx]));
}

__global__ __launch_bounds__(256) void pool2_kernel(
    const int* __restrict__ p1, const int* __restrict__ confb, int* __restrict__ p2)
{
    int idx = blockIdx.x * 256 + threadIdx.x;
    int c = idx >> 7, f = idx & 127;
    atomicMax(&p2[confb[c] * HH + f], p1[idx]);
}

// ---------------- output head ----------------
__global__ __launch_bounds__(128) void out_layer_kernel(
    const float* __restrict__ xm, const float* __restrict__ w1,
    const float* __restrict__ b1, const float* __restrict__ w2,
    const float* __restrict__ b2, float* __restrict__ out)
{
    int m = blockIdx.x, f = threadIdx.x;
    __shared__ float xs[128];
    xs[f] = xm[m * HH + f];
    __syncthreads();
    float acc = b1[f];
    for (int k = 0; k < 128; k++) acc = fmaf(xs[k], w1[k * HH + f], acc);
    acc = fmaxf(acc, 0.f) * w2[f];
    __shared__ float red[128];
    red[f] = acc;
    __syncthreads();
    for (int off = 64; off > 0; off >>= 1) {
        if (f < off) red[f] += red[f + off];
        __syncthreads();
    }
    if (f == 0) out[m] = red[0] + b2[0];
}

extern "C" void kernel_launch(void* const* d_in, const int* in_sizes, int n_in,
                              void* d_out, int out_size, void* d_ws, size_t ws_size,
                              hipStream_t stream)
{
    const int*   x_topo    = (const int*)d_in[0];
    const float* pos       = (const float*)d_in[1];
    const int*   eic       = (const int*)d_in[2];
    const int*   eig       = (const int*)d_in[3];
    const int*   eattr     = (const int*)d_in[4];
    const int*   cnb       = (const int*)d_in[5];
    const int*   posb      = (const int*)d_in[6];
    const int*   confb     = (const int*)d_in[7];
    const float* atom_emb  = (const float*)d_in[8];
    const float* cf_lin1_w = (const float*)d_in[9];
    const float* cf_mlp_w1 = (const float*)d_in[10];
    const float* cf_mlp_b1 = (const float*)d_in[11];
    const float* cf_mlp_w2 = (const float*)d_in[12];
    const float* cf_mlp_b2 = (const float*)d_in[13];
    const float* cf_lin2_w = (const float*)d_in[14];
    const float* cf_lin2_b = (const float*)d_in[15];
    const float* lin_w     = (const float*)d_in[16];
    const float* lin_b     = (const float*)d_in[17];
    const float* bond_emb  = (const float*)d_in[18];
    const float* gin_w1    = (const float*)d_in[19];
    const float* gin_b1    = (const float*)d_in[20];
    const float* gin_w2    = (const float*)d_in[21];
    const float* gin_b2    = (const float*)d_in[22];
    const float* gin_bn_g  = (const float*)d_in[23];
    const float* gin_bn_b  = (const float*)d_in[24];
    const float* bn_g      = (const float*)d_in[25];
    const float* bn_b      = (const float*)d_in[26];
    const float* gin_eps   = (const float*)d_in[27];
    const float* out_w1    = (const float*)d_in[28];
    const float* out_b1    = (const float*)d_in[29];
    const float* out_w2    = (const float*)d_in[30];
    const float* out_b2    = (const float*)d_in[31];
    float* out = (float*)d_out;

    char* wsb = (char*)d_ws;
    size_t off = 0;
    auto alloc = [&](size_t nbytes) -> void* {
        void* p = (void*)(wsb + off);
        off += (nbytes + 255) & ~(size_t)255;
        return p;
    };
    float*  ew      = (float*)alloc(EC * 4);
    float*  x       = (float*)alloc((size_t)NN * HH * 4);
    ushort* xb      = (ushort*)alloc((size_t)NN * HH * 2);
    ushort* h1b     = (ushort*)alloc((size_t)NN * FF * 2);
    ushort* aggb    = (ushort*)alloc((size_t)NN * FF * 2);
    ushort* h2b     = (ushort*)alloc((size_t)NN * HH * 2);
    float*  outb    = (float*)alloc((size_t)NN * HH * 4);
    unsigned int* enc = (unsigned int*)alloc((size_t)NT * HH * 4);
    float*  xagg    = (float*)alloc((size_t)NT * HH * 4);
    float*  magg    = (float*)alloc((size_t)NT * HH * 4);
    float*  hg0     = (float*)alloc((size_t)NT * HH * 4);
    float*  hgA     = (float*)alloc((size_t)NT * HH * 4);
    float*  hgB     = (float*)alloc((size_t)NT * HH * 4);
    float*  p1      = (float*)alloc((size_t)NCONF_ * HH * 4);
    float*  p2      = (float*)alloc((size_t)MM * HH * 4);
    float*  table   = (float*)alloc((size_t)TBL * 64 * 4);
    int*    deg     = (int*)alloc(NN * 4);
    int*    offs    = (int*)alloc((NN + 1) * 4);
    int*    cursor  = (int*)alloc(NN * 4);
    int*    bsum    = (int*)alloc(256 * 4);
    int*    boff    = (int*)alloc(256 * 4);
    int*    src_csr = (int*)alloc(EC * 4);
    float*  u_csr   = (float*)alloc(EC * 4);
    ushort* w1f     = (ushort*)alloc((size_t)HH * FF * 2);
    ushort* w2f     = (ushort*)alloc((size_t)FF * HH * 2);
    ushort* wlf     = (ushort*)alloc((size_t)HH * HH * 2);

    // --- geometry + embedding ---
    edge_geom_kernel<<<EC / 256, 256, 0, stream>>>(pos, eic, ew);
    embed_kernel<<<NN * HH / 256, 256, 0, stream>>>(atom_emb, x_topo, cnb, x, xb);

    // --- CSR by destination + edge-payload permute (once; reused by all layers) ---
    hipMemsetAsync(deg, 0, NN * 4, stream);
    hist_kernel<<<EC / 256, 256, 0, stream>>>(eic, deg);
    scan1_kernel<<<NN / 256, 256, 0, stream>>>(deg, offs, bsum);
    scan2_kernel<<<1, 256, 0, stream>>>(bsum, boff);
    scan3_kernel<<<NN / 256, 256, 0, stream>>>(offs, boff, cursor);
    scatter_kernel<<<EC / 256, 256, 0, stream>>>(eic, ew, cursor, src_csr, u_csr);

    for (int l = 0; l < 4; l++) {
        build_table_kernel<<<TBL, 64, 0, stream>>>(
            cf_mlp_w1 + (size_t)l * GG * FF, cf_mlp_b1 + (size_t)l * FF,
            cf_mlp_w2 + (size_t)l * FF * FF, cf_mlp_b2 + (size_t)l * FF, table);
        prep_w_kernel<<<HH * FF / 256, 256, 0, stream>>>(
            cf_lin1_w + (size_t)l * HH * FF, w1f, HH, FF);
        prep_w_kernel<<<FF * HH / 256, 256, 0, stream>>>(
            cf_lin2_w + (size_t)l * FF * HH, w2f, FF, HH);
        prep_w_kernel<<<HH * HH / 256, 256, 0, stream>>>(
            lin_w + (size_t)l * HH * HH, wlf, HH, HH);

        // h1b = xb @ cf_lin1_w[l]           [NN x 64], bf16 out
        gemm_bf16_kernel<<<NN / 64, 256, 0, stream>>>(
            xb, w1f, nullptr, nullptr, h1b, nullptr, NN, FF, HH, 0);
        // aggb[c] = sum_e h1b[src_e] * Wf(u_e)   (CSR, contiguous payload)
        edge_agg_csr_kernel<<<NN * 64 / 256, 256, 0, stream>>>(
            offs, src_csr, u_csr, table, h1b, aggb);
        // h2b = relu(aggb @ cf_lin2_w[l] + b)    [NN x 128], bf16 out
        gemm_bf16_kernel<<<NN / 64, 256, 0, stream>>>(
            aggb, w2f, cf_lin2_b + (size_t)l * HH, nullptr, h2b, nullptr, NN, HH, FF, 1);
        // outb = x + h2b @ lin_w[l] + lin_b[l]   fp32 out (residual in fp32)
        gemm_bf16_kernel<<<NN / 64, 256, 0, stream>>>(
            h2b, wlf, lin_b + (size_t)l * HH, x, nullptr, outb, NN, HH, HH, 0);

        // GIN branch on topo graph (fp32)
        hipMemsetAsync(enc, 0, (size_t)NT * HH * 4, stream);
        encode_max_kernel<<<NN * HH / 256, 256, 0, stream>>>(x, cnb, enc);
        decode_max_kernel<<<NT * HH / 256, 256, 0, stream>>>(enc, xagg);
        hipMemsetAsync(magg, 0, (size_t)NT * HH * 4, stream);
        magg_kernel<<<EG, 128, 0, stream>>>(
            xagg, eig, eattr, bond_emb + (size_t)l * 10 * HH, magg);
        hg0_kernel<<<NT * HH / 256, 256, 0, stream>>>(xagg, magg, gin_eps + l, hg0);
        gemm_kernel<<<dim3(HH / 64, NT / 64), 256, 0, stream>>>(
            hg0, gin_w1 + (size_t)l * HH * HH, gin_b1 + (size_t)l * HH,
            nullptr, hgA, NT, HH, HH, 0);
        bn_kernel<<<HH, 256, 0, stream>>>(
            hgA, gin_bn_g + (size_t)l * HH, gin_bn_b + (size_t)l * HH, NT, 1);
        gemm_kernel<<<dim3(HH / 64, NT / 64), 256, 0, stream>>>(
            hgA, gin_w2 + (size_t)l * HH * HH, gin_b2 + (size_t)l * HH,
            nullptr, hgB, NT, HH, HH, 0);
        bn_kernel<<<HH, 256, 0, stream>>>(
            hgB, bn_g + (size_t)l * HH, bn_b + (size_t)l * HH, NT, 0);
        combine_kernel<<<NN * HH / 256, 256, 0, stream>>>(outb, hgB, cnb, x, xb);
    }

    hipMemsetAsync(p1, 0, (size_t)NCONF_ * HH * 4, stream);
    hipMemsetAsync(p2, 0, (size_t)MM * HH * 4, stream);
    pool1_kernel<<<NN * HH / 256, 256, 0, stream>>>(x, posb, (int*)p1);
    pool2_kernel<<<NCONF_ * HH / 256, 256, 0, stream>>>((const int*)p1, confb, (int*)p2);
    out_layer_kernel<<<MM, 128, 0, stream>>>(p2, out_w1, out_b1, out_w2, out_b2, out);
}

// Round 6
// 1306.611 us; speedup vs baseline: 2.3004x; 1.3533x over previous
//
#include <hip/hip_runtime.h>
#include <hip/hip_bf16.h>

#define EC 1048576   // conformer edges
#define NN 65536     // conformer nodes
#define NT 8192      // topo nodes
#define NCONF_ 2048
#define MM 256
#define HH 128
#define FF 64
#define GG 50
#define EG 32768     // graph edges

#define TBL 8192            // Wf table entries
#define TRANGE 14.0f        // Wf(ew) == 0 beyond (b1=b2=0, gaussians dead)

constexpr float STEP = 10.0f / 49.0f;
constexpr float GC = -0.5f / (STEP * STEP);

typedef __attribute__((ext_vector_type(8))) short bf16x8;
typedef __attribute__((ext_vector_type(4))) float f32x4;

__device__ __forceinline__ ushort f2b(float v) {
    __hip_bfloat16 h = __float2bfloat16(v);
    return *(ushort*)&h;
}
__device__ __forceinline__ float b2f(ushort u) {
    return __uint_as_float(((unsigned)u) << 16);
}

// ---------------- edge geometry ----------------
__global__ __launch_bounds__(256) void edge_geom_kernel(
    const float* __restrict__ pos, const int* __restrict__ ei,
    float* __restrict__ ew)
{
    int e = blockIdx.x * 256 + threadIdx.x;
    int r = ei[e], c = ei[EC + e];
    float dx = pos[r*3+0] - pos[c*3+0];
    float dy = pos[r*3+1] - pos[c*3+1];
    float dz = pos[r*3+2] - pos[c*3+2];
    ew[e] = sqrtf(dx*dx + dy*dy + dz*dz + 1e-12f);
}

// ---------------- atom embedding broadcast (fp32 + bf16 copies) ----------------
__global__ __launch_bounds__(256) void embed_kernel(
    const float* __restrict__ emb, const int* __restrict__ xtopo,
    const int* __restrict__ cnb, float* __restrict__ x, ushort* __restrict__ xb)
{
    int idx = blockIdx.x * 256 + threadIdx.x;
    int n = idx >> 7, f = idx & 127;
    float v = emb[xtopo[cnb[n]] * HH + f];
    x[idx] = v;
    xb[idx] = f2b(v);
}

// ---------------- generic CSR build: histogram / scan / scatter ----------------
__global__ __launch_bounds__(256) void hist_kernel(
    const int* __restrict__ idx, int* __restrict__ deg)
{
    int e = blockIdx.x * 256 + threadIdx.x;
    atomicAdd(&deg[idx[e]], 1);
}

__global__ __launch_bounds__(256) void scan1_kernel(
    const int* __restrict__ deg, int* __restrict__ offs, int* __restrict__ bsum)
{
    __shared__ int s[256];
    int tid = threadIdx.x, b = blockIdx.x;
    int v = deg[b * 256 + tid];
    s[tid] = v;
    __syncthreads();
    for (int off = 1; off < 256; off <<= 1) {
        int t = (tid >= off) ? s[tid - off] : 0;
        __syncthreads();
        s[tid] += t;
        __syncthreads();
    }
    offs[b * 256 + tid] = s[tid] - v;
    if (tid == 255) bsum[b] = s[255];
}

__global__ __launch_bounds__(256) void scan2_kernel(
    const int* __restrict__ bsum, int* __restrict__ boff, int nb)
{
    __shared__ int s[256];
    int tid = threadIdx.x;
    int v = (tid < nb) ? bsum[tid] : 0;
    s[tid] = v;
    __syncthreads();
    for (int off = 1; off < 256; off <<= 1) {
        int t = (tid >= off) ? s[tid - off] : 0;
        __syncthreads();
        s[tid] += t;
        __syncthreads();
    }
    if (tid < nb) boff[tid] = s[tid] - v;
}

__global__ __launch_bounds__(256) void scan3_kernel(
    int* __restrict__ offs, const int* __restrict__ boff, int* __restrict__ cursor,
    int S, int E)
{
    int i = blockIdx.x * 256 + threadIdx.x;
    int v = offs[i] + boff[i >> 8];
    offs[i] = v;
    cursor[i] = v;
    if (i == 0) offs[S] = E;
}

// edge scatter: permute (src, scaled-distance) into CSR-by-dest order
__global__ __launch_bounds__(256) void scatter_edge_kernel(
    const int* __restrict__ eic, const float* __restrict__ ew,
    int* __restrict__ cursor, int* __restrict__ src_csr, float* __restrict__ u_csr)
{
    int e = blockIdx.x * 256 + threadIdx.x;
    int c = eic[EC + e];
    int p = atomicAdd(&cursor[c], 1);
    src_csr[p] = eic[e];
    u_csr[p] = ew[e] * ((TBL - 1) / TRANGE);
}

// cnb scatter: list of conformer-node ids per topo node
__global__ __launch_bounds__(256) void scatter_cnb_kernel(
    const int* __restrict__ cnb, int* __restrict__ cursor, int* __restrict__ list)
{
    int n = blockIdx.x * 256 + threadIdx.x;
    int p = atomicAdd(&cursor[cnb[n]], 1);
    list[p] = n;
}

// graph-edge scatter: (src topo node, bond type) per dest topo node
__global__ __launch_bounds__(256) void scatter_graph_kernel(
    const int* __restrict__ eig, const int* __restrict__ eattr,
    int* __restrict__ cursor, int* __restrict__ gsrc, int* __restrict__ gbt)
{
    int e = blockIdx.x * 256 + threadIdx.x;
    int p = atomicAdd(&cursor[eig[EG + e]], 1);
    gsrc[p] = eig[e];
    gbt[p] = eattr[e];
}

// ---------------- per-layer Wf table ----------------
__global__ __launch_bounds__(64) void build_table_kernel(
    const float* __restrict__ w1, const float* __restrict__ b1,
    const float* __restrict__ w2, const float* __restrict__ b2,
    float* __restrict__ table)
{
    int p = blockIdx.x, lane = threadIdx.x;
    float w = p * (TRANGE / (TBL - 1));
    float t = b1[lane];
    for (int g = 0; g < GG; g++) {
        float d = w - g * STEP;
        float ea = __expf(GC * d * d);
        t = fmaf(ea, w1[g * 64 + lane], t);
    }
    __shared__ float ts[64];
    ts[lane] = fmaxf(t, 0.f);
    __syncthreads();
    float wf = b2[lane];
    for (int i = 0; i < 64; i++)
        wf = fmaf(ts[i], w2[i * 64 + lane], wf);
    float cw = 0.5f * (__cosf(w * (3.14159265358979323846f / 10.0f)) + 1.0f);
    table[p * 64 + lane] = wf * cw;
}

// ---------------- weight prep: fp32 KxN -> bf16 MFMA-fragment order ----------------
__global__ __launch_bounds__(256) void prep_w_kernel(
    const float* __restrict__ W, ushort* __restrict__ Wf, int K, int N)
{
    int t = blockIdx.x * 256 + threadIdx.x;   // N*K total
    int j = t & 7;
    int lane = (t >> 3) & 63;
    int rest = t >> 9;
    int KTl = K >> 5;
    int kt = rest % KTl;
    int nt = rest / KTl;
    int k = kt * 32 + (lane >> 4) * 8 + j;
    int n = nt * 16 + (lane & 15);
    Wf[t] = f2b(W[(size_t)k * N + n]);
}

// ---------------- bf16 MFMA GEMM ----------------
// C = A[MxK] @ B[KxN] (+bias) (+res fp32) (+resg gathered via gidx) (relu)
// outputs: Cb (bf16) and/or Cf (fp32)
__global__ __launch_bounds__(256) void gemm_bf16_kernel(
    const ushort* __restrict__ A, const ushort* __restrict__ Bf,
    const float* __restrict__ bias, const float* __restrict__ res,
    const float* __restrict__ resg, const int* __restrict__ gidx,
    ushort* __restrict__ Cb, float* __restrict__ Cf,
    int M, int N, int K, int relu)
{
    int tid = threadIdx.x;
    int wave = tid >> 6, lane = tid & 63;
    int m0 = (blockIdx.x * 4 + wave) * 16;
    int ntile = N >> 4, ktile = K >> 5;
    int arow = m0 + (lane & 15);
    int ak = (lane >> 4) * 8;
    f32x4 acc[8];
    #pragma unroll
    for (int i = 0; i < 8; i++) acc[i] = (f32x4){0.f, 0.f, 0.f, 0.f};
    for (int kt = 0; kt < ktile; kt++) {
        bf16x8 a = *(const bf16x8*)(A + (size_t)arow * K + kt * 32 + ak);
        const ushort* bp = Bf + ((size_t)kt * 64 + lane) * 8;
        for (int nt = 0; nt < ntile; nt++) {
            bf16x8 b = *(const bf16x8*)(bp + (size_t)nt * ktile * 512);
            acc[nt] = __builtin_amdgcn_mfma_f32_16x16x32_bf16(a, b, acc[nt], 0, 0, 0);
        }
    }
    int col0 = lane & 15;
    int rbase = m0 + (lane >> 4) * 4;
    int cn[4];
    if (resg) {
        #pragma unroll
        for (int r = 0; r < 4; r++) cn[r] = gidx[rbase + r];
    }
    for (int nt = 0; nt < ntile; nt++) {
        int col = nt * 16 + col0;
        float bs = bias ? bias[col] : 0.f;
        #pragma unroll
        for (int r = 0; r < 4; r++) {
            int row = rbase + r;
            float v = acc[nt][r] + bs;
            if (res) v += res[(size_t)row * N + col];
            if (resg) v += resg[(size_t)cn[r] * N + col];
            if (relu) v = fmaxf(v, 0.f);
            if (Cf) Cf[(size_t)row * N + col] = v;
            if (Cb) Cb[(size_t)row * N + col] = f2b(v);
        }
    }
}

// ---------------- CSR edge aggregation: wave per node, 4-deep pipeline ----------------
__global__ __launch_bounds__(256) void edge_agg_csr_kernel(
    const int* __restrict__ offs, const int* __restrict__ src_csr,
    const float* __restrict__ u_csr, const float* __restrict__ table,
    const ushort* __restrict__ h1b, ushort* __restrict__ aggb)
{
    int node = (blockIdx.x * 256 + threadIdx.x) >> 6;
    int lane = threadIdx.x & 63;
    int beg = offs[node], end = offs[node + 1];
    const float UMAX = (float)(TBL - 2);   // clamp: table==0 exactly at far end
    float acc = 0.f;
    int p = beg;
    for (; p + 4 <= end; p += 4) {
        float u0 = fminf(u_csr[p+0], UMAX); int r0 = src_csr[p+0];
        float u1 = fminf(u_csr[p+1], UMAX); int r1 = src_csr[p+1];
        float u2 = fminf(u_csr[p+2], UMAX); int r2 = src_csr[p+2];
        float u3 = fminf(u_csr[p+3], UMAX); int r3 = src_csr[p+3];
        int i0 = (int)u0, i1 = (int)u1, i2 = (int)u2, i3 = (int)u3;
        float g0 = u0 - (float)i0, g1 = u1 - (float)i1;
        float g2 = u2 - (float)i2, g3 = u3 - (float)i3;
        float h0 = b2f(h1b[(size_t)r0 * 64 + lane]);
        float h1v = b2f(h1b[(size_t)r1 * 64 + lane]);
        float h2v = b2f(h1b[(size_t)r2 * 64 + lane]);
        float h3 = b2f(h1b[(size_t)r3 * 64 + lane]);
        float a0 = table[i0 * 64 + lane], c0 = table[i0 * 64 + 64 + lane];
        float a1 = table[i1 * 64 + lane], c1 = table[i1 * 64 + 64 + lane];
        float a2 = table[i2 * 64 + lane], c2 = table[i2 * 64 + 64 + lane];
        float a3 = table[i3 * 64 + lane], c3 = table[i3 * 64 + 64 + lane];
        acc = fmaf(h0, fmaf(c0 - a0, g0, a0), acc);
        acc = fmaf(h1v, fmaf(c1 - a1, g1, a1), acc);
        acc = fmaf(h2v, fmaf(c2 - a2, g2, a2), acc);
        acc = fmaf(h3, fmaf(c3 - a3, g3, a3), acc);
    }
    for (; p < end; p++) {
        float u = fminf(u_csr[p], UMAX);
        int r = src_csr[p];
        int i0 = (int)u;
        float fr = u - (float)i0;
        float t0 = table[i0 * 64 + lane];
        float t1 = table[i0 * 64 + 64 + lane];
        acc = fmaf(b2f(h1b[(size_t)r * 64 + lane]), fmaf(t1 - t0, fr, t0), acc);
    }
    aggb[(size_t)node * 64 + lane] = f2b(acc);
}

// ---------------- deterministic segment-max: xagg[tn][f] = max over cnb-list ----------------
__global__ __launch_bounds__(256) void xagg_max_kernel(
    const int* __restrict__ coffs, const int* __restrict__ clist,
    const float* __restrict__ x, float* __restrict__ xagg)
{
    int idx = blockIdx.x * 256 + threadIdx.x;   // NT*HH
    int tn = idx >> 7, f = idx & 127;
    int beg = coffs[tn], end = coffs[tn + 1];
    float m = -3.4e38f;
    for (int p = beg; p < end; p++)
        m = fmaxf(m, x[(size_t)clist[p] * HH + f]);
    xagg[idx] = m;
}

// ---------------- GIN: magg gather-sum + hg0, fused ----------------
__global__ __launch_bounds__(256) void magg_gin_kernel(
    const int* __restrict__ goffs, const int* __restrict__ gsrc,
    const int* __restrict__ gbt, const float* __restrict__ xagg,
    const float* __restrict__ bemb, const float* __restrict__ eps,
    float* __restrict__ hg0)
{
    int idx = blockIdx.x * 256 + threadIdx.x;   // NT*HH
    int tn = idx >> 7, f = idx & 127;
    int beg = goffs[tn], end = goffs[tn + 1];
    float acc = 0.f;
    for (int p = beg; p < end; p++) {
        float v = xagg[(size_t)gsrc[p] * HH + f] + bemb[gbt[p] * HH + f];
        acc += fmaxf(v, 0.f);
    }
    hg0[idx] = (1.0f + eps[0]) * xagg[idx] + acc;
}

// ---------------- generic fp32 GEMM (GIN branch, small) ----------------
__global__ __launch_bounds__(256) void gemm_kernel(
    const float* __restrict__ A, const float* __restrict__ B,
    const float* __restrict__ bias, const float* __restrict__ res,
    float* __restrict__ C, int M, int N, int K, int flags)
{
    __shared__ float As[16][68];
    __shared__ float Bs[16][68];
    int tid = threadIdx.x;
    int m0 = blockIdx.y * 64, n0 = blockIdx.x * 64;
    int la_m = tid >> 2;
    int la_k = (tid & 3) * 4;
    int lb_k = tid >> 4;
    int lb_n = (tid & 15) * 4;
    int tx = tid & 15, ty = tid >> 4;
    float acc[4][4] = {};
    const float* Ap = A + (size_t)(m0 + la_m) * K + la_k;
    const float* Bp = B + (size_t)lb_k * N + n0 + lb_n;
    for (int k0 = 0; k0 < K; k0 += 16) {
        float4 av = *(const float4*)(Ap + k0);
        float4 bv = *(const float4*)(Bp + (size_t)k0 * N);
        __syncthreads();
        As[la_k+0][la_m] = av.x; As[la_k+1][la_m] = av.y;
        As[la_k+2][la_m] = av.z; As[la_k+3][la_m] = av.w;
        *(float4*)&Bs[lb_k][lb_n] = bv;
        __syncthreads();
        #pragma unroll
        for (int kk = 0; kk < 16; kk++) {
            float4 a = *(const float4*)&As[kk][ty*4];
            float4 b = *(const float4*)&Bs[kk][tx*4];
            float ar[4] = {a.x, a.y, a.z, a.w};
            float br[4] = {b.x, b.y, b.z, b.w};
            #pragma unroll
            for (int i = 0; i < 4; i++)
                #pragma unroll
                for (int j = 0; j < 4; j++)
                    acc[i][j] = fmaf(ar[i], br[j], acc[i][j]);
        }
    }
    #pragma unroll
    for (int i = 0; i < 4; i++) {
        int row = m0 + ty*4 + i;
        #pragma unroll
        for (int j = 0; j < 4; j++) {
            int col = n0 + tx*4 + j;
            float v = acc[i][j];
            if (bias) v += bias[col];
            if (flags & 2) v += res[(size_t)row * N + col];
            if (flags & 1) v = fmaxf(v, 0.f);
            C[(size_t)row * N + col] = v;
        }
    }
}

// ---------------- batchnorm (training-mode batch stats), in-place ----------------
__global__ __launch_bounds__(256) void bn_kernel(
    float* __restrict__ X, const float* __restrict__ gamma,
    const float* __restrict__ beta, int rows, int relu)
{
    int f = blockIdx.x, tid = threadIdx.x;
    float s = 0.f, s2 = 0.f;
    for (int r = tid; r < rows; r += 256) {
        float v = X[(size_t)r * HH + f];
        s += v; s2 += v * v;
    }
    __shared__ float red[256], red2[256];
    red[tid] = s; red2[tid] = s2;
    __syncthreads();
    for (int off = 128; off > 0; off >>= 1) {
        if (tid < off) { red[tid] += red[tid + off]; red2[tid] += red2[tid + off]; }
        __syncthreads();
    }
    __shared__ float smu, sinv;
    if (tid == 0) {
        float mu = red[0] / rows;
        float var = red2[0] / rows - mu * mu;
        smu = mu; sinv = rsqrtf(var + 1e-5f);
    }
    __syncthreads();
    float g = gamma[f], b = beta[f], mu = smu, inv = sinv;
    for (int r = tid; r < rows; r += 256) {
        float v = (X[(size_t)r * HH + f] - mu) * inv * g + b;
        if (relu) v = fmaxf(v, 0.f);
        X[(size_t)r * HH + f] = v;
    }
}

// ---------------- pooling ----------------
__global__ __launch_bounds__(256) void pool1_kernel(
    const float* __restrict__ x, const int* __restrict__ posb, int* __restrict__ p1)
{
    int idx = blockIdx.x * 256 + threadIdx.x;
    int n = idx >> 7, f = idx & 127;
    atomicMax(&p1[posb[n] * HH + f], __float_as_int(x[idx]));
}

__global__ __launch_bounds__(256) void pool2_kernel(
    const int* __restrict__ p1, const int* __restrict__ confb, int* __restrict__ p2)
{
    int idx = blockIdx.x * 256 + threadIdx.x;
    int c = idx >> 7, f = idx & 127;
    atomicMax(&p2[confb[c] * HH + f], p1[idx]);
}

// ---------------- output head ----------------
__global__ __launch_bounds__(128) void out_layer_kernel(
    const float* __restrict__ xm, const float* __restrict__ w1,
    const float* __restrict__ b1, const float* __restrict__ w2,
    const float* __restrict__ b2, float* __restrict__ out)
{
    int m = blockIdx.x, f = threadIdx.x;
    __shared__ float xs[128];
    xs[f] = xm[m * HH + f];
    __syncthreads();
    float acc = b1[f];
    for (int k = 0; k < 128; k++) acc = fmaf(xs[k], w1[k * HH + f], acc);
    acc = fmaxf(acc, 0.f) * w2[f];
    __shared__ float red[128];
    red[f] = acc;
    __syncthreads();
    for (int off = 64; off > 0; off >>= 1) {
        if (f < off) red[f] += red[f + off];
        __syncthreads();
    }
    if (f == 0) out[m] = red[0] + b2[0];
}

extern "C" void kernel_launch(void* const* d_in, const int* in_sizes, int n_in,
                              void* d_out, int out_size, void* d_ws, size_t ws_size,
                              hipStream_t stream)
{
    const int*   x_topo    = (const int*)d_in[0];
    const float* pos       = (const float*)d_in[1];
    const int*   eic       = (const int*)d_in[2];
    const int*   eig       = (const int*)d_in[3];
    const int*   eattr     = (const int*)d_in[4];
    const int*   cnb       = (const int*)d_in[5];
    const int*   posb      = (const int*)d_in[6];
    const int*   confb     = (const int*)d_in[7];
    const float* atom_emb  = (const float*)d_in[8];
    const float* cf_lin1_w = (const float*)d_in[9];
    const float* cf_mlp_w1 = (const float*)d_in[10];
    const float* cf_mlp_b1 = (const float*)d_in[11];
    const float* cf_mlp_w2 = (const float*)d_in[12];
    const float* cf_mlp_b2 = (const float*)d_in[13];
    const float* cf_lin2_w = (const float*)d_in[14];
    const float* cf_lin2_b = (const float*)d_in[15];
    const float* lin_w     = (const float*)d_in[16];
    const float* lin_b     = (const float*)d_in[17];
    const float* bond_emb  = (const float*)d_in[18];
    const float* gin_w1    = (const float*)d_in[19];
    const float* gin_b1    = (const float*)d_in[20];
    const float* gin_w2    = (const float*)d_in[21];
    const float* gin_b2    = (const float*)d_in[22];
    const float* gin_bn_g  = (const float*)d_in[23];
    const float* gin_bn_b  = (const float*)d_in[24];
    const float* bn_g      = (const float*)d_in[25];
    const float* bn_b      = (const float*)d_in[26];
    const float* gin_eps   = (const float*)d_in[27];
    const float* out_w1    = (const float*)d_in[28];
    const float* out_b1    = (const float*)d_in[29];
    const float* out_w2    = (const float*)d_in[30];
    const float* out_b2    = (const float*)d_in[31];
    float* out = (float*)d_out;

    char* wsb = (char*)d_ws;
    size_t off = 0;
    auto alloc = [&](size_t nbytes) -> void* {
        void* p = (void*)(wsb + off);
        off += (nbytes + 255) & ~(size_t)255;
        return p;
    };
    float*  ew      = (float*)alloc(EC * 4);
    float*  x       = (float*)alloc((size_t)NN * HH * 4);
    ushort* xb      = (ushort*)alloc((size_t)NN * HH * 2);
    ushort* h1b     = (ushort*)alloc((size_t)NN * FF * 2);
    ushort* aggb    = (ushort*)alloc((size_t)NN * FF * 2);
    ushort* h2b     = (ushort*)alloc((size_t)NN * HH * 2);
    float*  xagg    = (float*)alloc((size_t)NT * HH * 4);
    float*  hg0     = (float*)alloc((size_t)NT * HH * 4);
    float*  hgA     = (float*)alloc((size_t)NT * HH * 4);
    float*  hgB     = (float*)alloc((size_t)NT * HH * 4);
    float*  p1      = (float*)alloc((size_t)NCONF_ * HH * 4);
    float*  p2      = (float*)alloc((size_t)MM * HH * 4);
    float*  table   = (float*)alloc((size_t)TBL * 64 * 4);
    int*    deg     = (int*)alloc(NN * 4);
    int*    offs    = (int*)alloc((NN + 1) * 4);
    int*    cursor  = (int*)alloc(NN * 4);
    int*    bsum    = (int*)alloc(256 * 4);
    int*    boff    = (int*)alloc(256 * 4);
    int*    src_csr = (int*)alloc(EC * 4);
    float*  u_csr   = (float*)alloc(EC * 4);
    int*    coffs   = (int*)alloc((NT + 1) * 4);
    int*    clist   = (int*)alloc(NN * 4);
    int*    goffs   = (int*)alloc((NT + 1) * 4);
    int*    gsrc    = (int*)alloc(EG * 4);
    int*    gbt     = (int*)alloc(EG * 4);
    ushort* w1f     = (ushort*)alloc((size_t)HH * FF * 2);
    ushort* w2f     = (ushort*)alloc((size_t)FF * HH * 2);
    ushort* wlf     = (ushort*)alloc((size_t)HH * HH * 2);

    // --- geometry + embedding ---
    edge_geom_kernel<<<EC / 256, 256, 0, stream>>>(pos, eic, ew);
    embed_kernel<<<NN * HH / 256, 256, 0, stream>>>(atom_emb, x_topo, cnb, x, xb);

    // --- CSR #1: conformer edges by destination ---
    hipMemsetAsync(deg, 0, NN * 4, stream);
    hist_kernel<<<EC / 256, 256, 0, stream>>>(eic + EC, deg);
    scan1_kernel<<<NN / 256, 256, 0, stream>>>(deg, offs, bsum);
    scan2_kernel<<<1, 256, 0, stream>>>(bsum, boff, NN / 256);
    scan3_kernel<<<NN / 256, 256, 0, stream>>>(offs, boff, cursor, NN, EC);
    scatter_edge_kernel<<<EC / 256, 256, 0, stream>>>(eic, ew, cursor, src_csr, u_csr);

    // --- CSR #2: conformer nodes per topo node (for segment_max) ---
    hipMemsetAsync(deg, 0, NT * 4, stream);
    hist_kernel<<<NN / 256, 256, 0, stream>>>(cnb, deg);
    scan1_kernel<<<NT / 256, 256, 0, stream>>>(deg, coffs, bsum);
    scan2_kernel<<<1, 256, 0, stream>>>(bsum, boff, NT / 256);
    scan3_kernel<<<NT / 256, 256, 0, stream>>>(coffs, boff, cursor, NT, NN);
    scatter_cnb_kernel<<<NN / 256, 256, 0, stream>>>(cnb, cursor, clist);

    // --- CSR #3: graph edges by destination (for GIN segment_sum) ---
    hipMemsetAsync(deg, 0, NT * 4, stream);
    hist_kernel<<<EG / 256, 256, 0, stream>>>(eig + EG, deg);
    scan1_kernel<<<NT / 256, 256, 0, stream>>>(deg, goffs, bsum);
    scan2_kernel<<<1, 256, 0, stream>>>(bsum, boff, NT / 256);
    scan3_kernel<<<NT / 256, 256, 0, stream>>>(goffs, boff, cursor, NT, EG);
    scatter_graph_kernel<<<EG / 256, 256, 0, stream>>>(eig, eattr, cursor, gsrc, gbt);

    for (int l = 0; l < 4; l++) {
        build_table_kernel<<<TBL, 64, 0, stream>>>(
            cf_mlp_w1 + (size_t)l * GG * FF, cf_mlp_b1 + (size_t)l * FF,
            cf_mlp_w2 + (size_t)l * FF * FF, cf_mlp_b2 + (size_t)l * FF, table);
        prep_w_kernel<<<HH * FF / 256, 256, 0, stream>>>(
            cf_lin1_w + (size_t)l * HH * FF, w1f, HH, FF);
        prep_w_kernel<<<FF * HH / 256, 256, 0, stream>>>(
            cf_lin2_w + (size_t)l * FF * HH, w2f, FF, HH);
        prep_w_kernel<<<HH * HH / 256, 256, 0, stream>>>(
            lin_w + (size_t)l * HH * HH, wlf, HH, HH);

        // h1b = xb @ cf_lin1_w[l]
        gemm_bf16_kernel<<<NN / 64, 256, 0, stream>>>(
            xb, w1f, nullptr, nullptr, nullptr, nullptr, h1b, nullptr, NN, FF, HH, 0);
        // aggb[c] = sum_e h1b[src_e] * Wf(u_e)
        edge_agg_csr_kernel<<<NN * 64 / 256, 256, 0, stream>>>(
            offs, src_csr, u_csr, table, h1b, aggb);
        // h2b = relu(aggb @ cf_lin2_w[l] + b)
        gemm_bf16_kernel<<<NN / 64, 256, 0, stream>>>(
            aggb, w2f, cf_lin2_b + (size_t)l * HH, nullptr, nullptr, nullptr,
            h2b, nullptr, NN, HH, FF, 1);

        // GIN branch (reads x BEFORE it is overwritten below)
        xagg_max_kernel<<<NT * HH / 256, 256, 0, stream>>>(coffs, clist, x, xagg);
        magg_gin_kernel<<<NT * HH / 256, 256, 0, stream>>>(
            goffs, gsrc, gbt, xagg, bond_emb + (size_t)l * 10 * HH, gin_eps + l, hg0);
        gemm_kernel<<<dim3(HH / 64, NT / 64), 256, 0, stream>>>(
            hg0, gin_w1 + (size_t)l * HH * HH, gin_b1 + (size_t)l * HH,
            nullptr, hgA, NT, HH, HH, 0);
        bn_kernel<<<HH, 256, 0, stream>>>(
            hgA, gin_bn_g + (size_t)l * HH, gin_bn_b + (size_t)l * HH, NT, 1);
        gemm_kernel<<<dim3(HH / 64, NT / 64), 256, 0, stream>>>(
            hgA, gin_w2 + (size_t)l * HH * HH, gin_b2 + (size_t)l * HH,
            nullptr, hgB, NT, HH, HH, 0);
        bn_kernel<<<HH, 256, 0, stream>>>(
            hgB, bn_g + (size_t)l * HH, bn_b + (size_t)l * HH, NT, 0);

        // fused: x = relu(x + h2b@lin_w + lin_b + hgB[cnb])  -> x (fp32) + xb (bf16)
        gemm_bf16_kernel<<<NN / 64, 256, 0, stream>>>(
            h2b, wlf, lin_b + (size_t)l * HH, x, hgB, cnb, xb, x, NN, HH, HH, 1);
    }

    hipMemsetAsync(p1, 0, (size_t)NCONF_ * HH * 4, stream);
    hipMemsetAsync(p2, 0, (size_t)MM * HH * 4, stream);
    pool1_kernel<<<NN * HH / 256, 256, 0, stream>>>(x, posb, (int*)p1);
    pool2_kernel<<<NCONF_ * HH / 256, 256, 0, stream>>>((const int*)p1, confb, (int*)p2);
    out_layer_kernel<<<MM, 128, 0, stream>>>(p2, out_w1, out_b1, out_w2, out_b2, out);
}